// Round 2
// baseline (316.084 us; speedup 1.0000x reference)
//
#include <hip/hip_runtime.h>
#include <math.h>

// Problem constants
#define CC 3
#define HH 1280
#define WW 720
#define BSZ 20
#define NHB 64
#define NWB 36
#define NBLK (NHB*NWB)          // 2304
#define OUT_IMG (3*5120*2880)   // 44236800

// Union'd LDS: light and gate are block-uniform branches of one kernel.
union __align__(16) SMem {
  struct {
    float in_s[3][22][28];      // zero-padded input block; pitch 28 (7 coprime 8 -> ~2-way banks)
    float w_t[27][48];          // transposed weights: [k=(ic*3+ky)*3+kx][oc] -> float4 per 4-oc group
    float b_s[48];
  } L;                           // 12768 B
  struct {
    float ins[3][26][28];       // clamped input patch (edge pad baked in)
    float w1t[27][16];          // transposed conv1 weights [k][oc]
    float b1s[16];
    float w2s[8*16*9];
    float b2s[8];
    float w3s[200];
    float x1s[16][12][14];      // post-pool conv1 patch, cols padded to 14 (8B-aligned float2)
    float red[256];
    float b3s;
  } G;                           // ~27.8 KB
};

__device__ __forceinline__ float fast_tanh(float x) {
  const float ax = fabsf(x);
  const float e = __expf(-2.0f * ax);          // v_exp_f32 path
  const float t = (1.0f - e) / (1.0f + e);
  return x < 0.0f ? -t : t;
}

// ---------------------------------------------------------------------------
// Light expert: per 20x20 block, zero-pad conv3x3 (3->48) + pixel_shuffle(4)
// + clamp[0,0.6]+0.4. mask always False -> complex expert dead.
// Thread = (h, ocg): 4 output channels sharing (c,r1), varying r2 -> the
// thread's 80 outputs form ONE contiguous output row -> direct float4 stores.
// LDS row reads amortized 4x vs round-1 (54 ds_read_b128/thread, one pass).
// ---------------------------------------------------------------------------
__device__ __forceinline__ void light_body(
    SMem& sm, int l,
    const float* __restrict__ inp,
    const float* __restrict__ wl,
    const float* __restrict__ bl,
    float* __restrict__ out) {
  const int bi = l / NWB, bj = l % NWB;
  const int tid = threadIdx.x;

  // transposed weight staging: w_t[k][oc] = wl[oc*27 + k]
  for (int i = tid; i < 27*48; i += 256) {
    int k = i / 48, oc = i - k*48;
    sm.L.w_t[k][oc] = wl[oc*27 + k];
  }
  if (tid < 48) sm.L.b_s[tid] = bl[tid];
  for (int i = tid; i < 3*22*28; i += 256) ((float*)sm.L.in_s)[i] = 0.0f;
  __syncthreads();
  // stage 20x20x3 block; global float4 loads (WW=720 and 20*bj are mult of 4)
  for (int i = tid; i < 300; i += 256) {
    int x4 = i % 5; int r = (i / 5) % 20; int c = i / 100;
    const float4 v = *(const float4*)&inp[(c*HH + bi*BSZ + r)*WW + bj*BSZ + 4*x4];
    float* dst = &sm.L.in_s[c][r+1][1 + 4*x4];
    dst[0] = v.x; dst[1] = v.y; dst[2] = v.z; dst[3] = v.w;
  }
  __syncthreads();

  if (tid < 240) {
    const int h   = tid % 20;
    const int ocg = tid / 20;            // 0..11 ; oc = 4*ocg + q
    const int c   = ocg >> 2;            // pixel-shuffle: c = oc>>4
    const int r1  = ocg & 3;             //                r1 = (oc>>2)&3 ; r2 = q

    float acc[4][20];
    {
      const float4 b4 = *(const float4*)&sm.L.b_s[4*ocg];
      #pragma unroll
      for (int w = 0; w < 20; ++w) {
        acc[0][w] = b4.x; acc[1][w] = b4.y; acc[2][w] = b4.z; acc[3][w] = b4.w;
      }
    }

    #pragma unroll
    for (int ic = 0; ic < 3; ++ic)
      #pragma unroll
      for (int ky = 0; ky < 3; ++ky) {
        const float* row = &sm.L.in_s[ic][h + ky][0];
        float r[24];
        #pragma unroll
        for (int j = 0; j < 6; ++j) {
          float4 v = ((const float4*)row)[j];          // ds_read_b128
          r[4*j+0] = v.x; r[4*j+1] = v.y; r[4*j+2] = v.z; r[4*j+3] = v.w;
        }
        const int kbase = (ic*3 + ky)*3;
        #pragma unroll
        for (int kx = 0; kx < 3; ++kx) {
          const float4 wv = *(const float4*)&sm.L.w_t[kbase + kx][4*ocg];
          #pragma unroll
          for (int w = 0; w < 20; ++w) {
            acc[0][w] += r[w+kx]*wv.x;
            acc[1][w] += r[w+kx]*wv.y;
            acc[2][w] += r[w+kx]*wv.z;
            acc[3][w] += r[w+kx]*wv.w;
          }
        }
      }

    // direct store: out[c][bi*80 + 4h + r1][bj*80 + 4w + q], q = float4 lane
    const int gy = bi*80 + 4*h + r1;
    float* orow = &out[(c*5120 + gy)*2880 + bj*80];
    #pragma unroll
    for (int w = 0; w < 20; ++w) {
      float4 v;
      v.x = fminf(fmaxf(acc[0][w], 0.0f), 0.6f) + 0.4f;
      v.y = fminf(fmaxf(acc[1][w], 0.0f), 0.6f) + 0.4f;
      v.z = fminf(fmaxf(acc[2][w], 0.0f), 0.6f) + 0.4f;
      v.w = fminf(fmaxf(acc[3][w], 0.0f), 0.6f) + 0.4f;
      *(float4*)&orow[4*w] = v;
    }
  }
}

// ---------------------------------------------------------------------------
// Fused gate CNN:
//   stage A: conv1(3->16, edge-pad) + tanh + maxpool2 on a local 12x12 patch
//            thread = (ocq, pos): 4 oc per patch load (patch LDS reads /4)
//   stage B: conv2(16->8, edge-pad) + maxpool2 -> 8x5x5 window
//   stage C: 5x5x8 dot (conv3 stride 5) + sigmoid -> 1 scalar
// ---------------------------------------------------------------------------
__device__ __forceinline__ void gate_body(
    SMem& sm, int l,
    const float* __restrict__ inp,
    const float* __restrict__ w1,
    const float* __restrict__ b1,
    const float* __restrict__ w2,
    const float* __restrict__ b2,
    const float* __restrict__ w3,
    const float* __restrict__ b3,
    float* __restrict__ cv) {
  const int tid = threadIdx.x;
  const int oy = l / NWB, ox = l % NWB;

  // transposed conv1 weights: w1t[k][oc] = w1[oc*27 + k]
  for (int i = tid; i < 27*16; i += 256) {
    int k = i >> 4, oc = i & 15;
    sm.G.w1t[k][oc] = w1[oc*27 + k];
  }
  for (int i = tid; i < 8*16*9; i += 256) sm.G.w2s[i] = w2[i];
  for (int i = tid; i < 200; i += 256) sm.G.w3s[i] = w3[i];
  if (tid < 16) sm.G.b1s[tid] = b1[tid];
  if (tid < 8)  sm.G.b2s[tid] = b2[tid];
  if (tid == 0) sm.G.b3s = b3[0];

  // input patch rows [20*oy-3, 20*oy+23), cols [20*ox-3, 20*ox+23), clamped
  for (int i = tid; i < 3*26*28; i += 256) {
    int b = i % 28; int a = (i / 28) % 26; int ic = i / (26*28);
    int gy = 20*oy - 3 + a; gy = gy < 0 ? 0 : (gy > HH-1 ? HH-1 : gy);
    int gx = 20*ox - 3 + b; gx = gx < 0 ? 0 : (gx > WW-1 ? WW-1 : gx);
    sm.G.ins[ic][a][b] = inp[(ic*HH + gy)*WW + gx];
  }
  __syncthreads();

  // ---- stage A: 4 oc per thread-iteration, patch loaded once per 4 oc
  for (int idx = tid; idx < 4*144; idx += 256) {
    const int ocq = idx / 144;                 // 0..3 -> oc = 4*ocq + q
    const int pos = idx - ocq*144;
    const int ly = pos / 12, lx = pos - ly*12;
    int y1 = 10*oy - 1 + ly; y1 = y1 < 0 ? 0 : (y1 > 639 ? 639 : y1);
    int x1 = 10*ox - 1 + lx; x1 = x1 < 0 ? 0 : (x1 > 359 ? 359 : x1);
    const int ry = 2*y1 + 2 - 20*oy;           // even, in [0,22]
    const int rx = 2*x1 + 2 - 20*ox;           // even, in [0,24]

    float patch[3][4][4];
    #pragma unroll
    for (int ic = 0; ic < 3; ++ic)
      #pragma unroll
      for (int d = 0; d < 4; ++d) {
        const float2 pa = *(const float2*)&sm.G.ins[ic][ry + d][rx];
        const float2 pb = *(const float2*)&sm.G.ins[ic][ry + d][rx + 2];
        patch[ic][d][0] = pa.x; patch[ic][d][1] = pa.y;
        patch[ic][d][2] = pb.x; patch[ic][d][3] = pb.y;
      }

    const float4 b4 = *(const float4*)&sm.G.b1s[4*ocq];
    float a00[4], a01[4], a10[4], a11[4];
    #pragma unroll
    for (int q = 0; q < 4; ++q) {
      const float bq = q == 0 ? b4.x : (q == 1 ? b4.y : (q == 2 ? b4.z : b4.w));
      a00[q] = bq; a01[q] = bq; a10[q] = bq; a11[q] = bq;
    }

    #pragma unroll
    for (int ic = 0; ic < 3; ++ic)
      #pragma unroll
      for (int ky = 0; ky < 3; ++ky)
        #pragma unroll
        for (int kx = 0; kx < 3; ++kx) {
          const int k = (ic*3 + ky)*3 + kx;
          const float4 wv = *(const float4*)&sm.G.w1t[k][4*ocq];
          const float p00 = patch[ic][ky  ][kx  ];
          const float p01 = patch[ic][ky  ][kx+1];
          const float p10 = patch[ic][ky+1][kx  ];
          const float p11 = patch[ic][ky+1][kx+1];
          a00[0] += p00*wv.x; a00[1] += p00*wv.y; a00[2] += p00*wv.z; a00[3] += p00*wv.w;
          a01[0] += p01*wv.x; a01[1] += p01*wv.y; a01[2] += p01*wv.z; a01[3] += p01*wv.w;
          a10[0] += p10*wv.x; a10[1] += p10*wv.y; a10[2] += p10*wv.z; a10[3] += p10*wv.w;
          a11[0] += p11*wv.x; a11[1] += p11*wv.y; a11[2] += p11*wv.z; a11[3] += p11*wv.w;
        }

    #pragma unroll
    for (int q = 0; q < 4; ++q) {
      const float m = fmaxf(fmaxf(a00[q], a01[q]), fmaxf(a10[q], a11[q]));
      // tanh monotonic: maxpool(tanh(.)) == tanh(maxpool(.))
      sm.G.x1s[4*ocq + q][ly][lx] = fast_tanh(m);
    }
  }
  __syncthreads();

  // ---- stage B
  float prod = 0.0f;
  if (tid < 200) {
    int oc2 = tid / 25; int rem = tid - oc2*25; int j = rem / 5; int i5 = rem - j*5;
    float a00 = sm.G.b2s[oc2], a01 = a00, a10 = a00, a11 = a00;
    for (int ic = 0; ic < 16; ++ic) {
      float p[4][4];
      #pragma unroll
      for (int d = 0; d < 4; ++d) {
        const float2 pa = *(const float2*)&sm.G.x1s[ic][2*j + d][2*i5];
        const float2 pb = *(const float2*)&sm.G.x1s[ic][2*j + d][2*i5 + 2];
        p[d][0] = pa.x; p[d][1] = pa.y; p[d][2] = pb.x; p[d][3] = pb.y;
      }
      #pragma unroll
      for (int ky = 0; ky < 3; ++ky)
        #pragma unroll
        for (int kx = 0; kx < 3; ++kx) {
          float wv = sm.G.w2s[((oc2*16 + ic)*3 + ky)*3 + kx];
          a00 += p[ky  ][kx  ]*wv;
          a01 += p[ky  ][kx+1]*wv;
          a10 += p[ky+1][kx  ]*wv;
          a11 += p[ky+1][kx+1]*wv;
        }
    }
    float x2 = fmaxf(fmaxf(a00, a01), fmaxf(a10, a11));
    prod = x2 * sm.G.w3s[tid];          // w3 index (oc2*5+j)*5+i5 == tid
  }
  sm.G.red[tid] = prod;
  __syncthreads();

  // ---- stage C
  if (tid < 64) {
    float s = sm.G.red[tid] + sm.G.red[tid+64] + sm.G.red[tid+128] + sm.G.red[tid+192];
    #pragma unroll
    for (int off = 32; off > 0; off >>= 1) s += __shfl_down(s, off);
    if (tid == 0)
      cv[l] = 1.0f / (1.0f + expf(-(s + sm.G.b3s)));
  }
}

// ---------------------------------------------------------------------------
// One launch, interleaved light/gate blocks (block-uniform branch).
// ---------------------------------------------------------------------------
__global__ __launch_bounds__(256) void fused_kernel(
    const float* __restrict__ inp,
    const float* __restrict__ w1,
    const float* __restrict__ b1,
    const float* __restrict__ w2,
    const float* __restrict__ b2,
    const float* __restrict__ w3,
    const float* __restrict__ b3,
    const float* __restrict__ wl,
    const float* __restrict__ bl,
    float* __restrict__ out) {
  __shared__ SMem sm;
  const int bid = blockIdx.x;
  if (bid & 1)
    gate_body(sm, bid >> 1, inp, w1, b1, w2, b2, w3, b3, out + OUT_IMG);
  else
    light_body(sm, bid >> 1, inp, wl, bl, out);
}

// ---------------------------------------------------------------------------
extern "C" void kernel_launch(void* const* d_in, const int* in_sizes, int n_in,
                              void* d_out, int out_size, void* d_ws, size_t ws_size,
                              hipStream_t stream) {
  const float* inp = (const float*)d_in[0];
  const float* w1  = (const float*)d_in[1];
  const float* b1  = (const float*)d_in[2];
  const float* w2  = (const float*)d_in[3];
  const float* b2  = (const float*)d_in[4];
  const float* w3  = (const float*)d_in[5];
  const float* b3  = (const float*)d_in[6];
  const float* wl  = (const float*)d_in[7];
  const float* bl  = (const float*)d_in[8];
  // d_in[9..14] = wc1,bc1,wc2,bc2,wc3,bc3: dead (gate sigmoid <= 1 -> mask always False)

  float* out = (float*)d_out;

  hipLaunchKernelGGL(fused_kernel, dim3(2*NBLK), dim3(256), 0, stream,
                     inp, w1, b1, w2, b2, w3, b3, wl, bl, out);
}